// Round 1
// baseline (1448.877 us; speedup 1.0000x reference)
//
#include <hip/hip_runtime.h>
#include <hip/hip_bf16.h>

#define RN 4096
#define EN 131072
#define TN 1536
#define PN 256
#define NBOUNCE 12
// np.float32(np.log(1e-3))
#define LOG_GAMMA -6.90775528f
#define INV_SR (1.0f / 16000.0f)

// ---------------- CSR build ----------------

__global__ void hist_kernel(const int* __restrict__ row, int* __restrict__ cnt) {
    int e = blockIdx.x * blockDim.x + threadIdx.x;
    if (e < EN) atomicAdd(&cnt[row[e]], 1);
}

// single block, 1024 threads: exclusive scan of cnt[0..RN) -> off[0..RN], off[RN]=EN
__global__ void scan_kernel(const int* __restrict__ cnt, int* __restrict__ off,
                            int* __restrict__ cursor) {
    __shared__ int part[1024];
    int tid = threadIdx.x;
    int v0 = cnt[tid * 4 + 0], v1 = cnt[tid * 4 + 1];
    int v2 = cnt[tid * 4 + 2], v3 = cnt[tid * 4 + 3];
    part[tid] = v0 + v1 + v2 + v3;
    __syncthreads();
    for (int ofs = 1; ofs < 1024; ofs <<= 1) {
        int x = (tid >= ofs) ? part[tid - ofs] : 0;
        __syncthreads();
        part[tid] += x;
        __syncthreads();
    }
    int excl = (tid == 0) ? 0 : part[tid - 1];
    int o0 = excl, o1 = o0 + v0, o2 = o1 + v1, o3 = o2 + v2;
    off[tid * 4 + 0] = o0; cursor[tid * 4 + 0] = o0;
    off[tid * 4 + 1] = o1; cursor[tid * 4 + 1] = o1;
    off[tid * 4 + 2] = o2; cursor[tid * 4 + 2] = o2;
    off[tid * 4 + 3] = o3; cursor[tid * 4 + 3] = o3;
    if (tid == 1023) off[RN] = o3 + v3;
}

// per edge: compute kernel value, place (col|delay<<12, kern) into CSR slot
__global__ void scatter_kernel(const int* __restrict__ row, const int* __restrict__ col,
                               const int* __restrict__ rid, const int* __restrict__ delay,
                               const float* __restrict__ basis,
                               const float* __restrict__ absorption,
                               const float* __restrict__ scattering,
                               int* __restrict__ cursor,
                               int* __restrict__ packed, float* __restrict__ kernv) {
    int e = blockIdx.x * blockDim.x + threadIdx.x;
    if (e >= EN) return;
    int p = rid[e];
    float a = absorption[p];
    float s = scattering[p];
    float k = (1.0f - a) * (s * basis[e] + (1.0f - s) * basis[EN + e]);
    int r = row[e];
    int pos = atomicAdd(&cursor[r], 1);
    packed[pos] = col[e] | (delay[e] << 12);
    kernv[pos] = k;
}

// ---------------- init: cur = tot = x * window ----------------

__global__ void init_kernel(const float* __restrict__ x, float* __restrict__ cur,
                            float* __restrict__ tot) {
    int g = blockIdx.x * blockDim.x + threadIdx.x;   // one float4 per thread
    if (g >= RN * TN / 4) return;
    int t4 = g % (TN / 4);
    int tbase = t4 * 4;
    const float4 v = reinterpret_cast<const float4*>(x)[g];
    float4 o;
    o.x = v.x * __expf(LOG_GAMMA * (float)(tbase + 0) * INV_SR);
    o.y = v.y * __expf(LOG_GAMMA * (float)(tbase + 1) * INV_SR);
    o.z = v.z * __expf(LOG_GAMMA * (float)(tbase + 2) * INV_SR);
    o.w = v.w * __expf(LOG_GAMMA * (float)(tbase + 3) * INV_SR);
    reinterpret_cast<float4*>(cur)[g] = o;
    reinterpret_cast<float4*>(tot)[g] = o;
}

// ---------------- bounce: nxt[r,t] = sum_e kern*cur[col,(t-d) mod T]; tot += nxt ----

__global__ __launch_bounds__(256) void bounce_kernel(
        const float* __restrict__ cur, float* __restrict__ nxt, float* __restrict__ tot,
        const int* __restrict__ off, const int* __restrict__ packed,
        const float* __restrict__ kernv) {
    int r = blockIdx.x;
    int tid = threadIdx.x;
    int e0 = off[r], e1 = off[r + 1];
    float acc[6] = {0.f, 0.f, 0.f, 0.f, 0.f, 0.f};
    __shared__ int   s_pk[128];
    __shared__ float s_kv[128];
    for (int base = e0; base < e1; base += 128) {
        int n = min(128, e1 - base);
        __syncthreads();
        if (tid < n) { s_pk[tid] = packed[base + tid]; s_kv[tid] = kernv[base + tid]; }
        __syncthreads();
        for (int j = 0; j < n; ++j) {
            int pk = s_pk[j];
            int c = pk & 4095;
            int d = pk >> 12;
            float k = s_kv[j];
            const float* rowp = cur + c * TN;
            int u = tid - d + TN;                 // [1025, 1791]
#pragma unroll
            for (int kk = 0; kk < 6; ++kk) {
                int idx = u + kk * 256;           // max 3071 < 2*TN
                if (idx >= TN) idx -= TN;
                acc[kk] = fmaf(k, rowp[idx], acc[kk]);
            }
        }
    }
#pragma unroll
    for (int kk = 0; kk < 6; ++kk) {
        int t = tid + kk * 256;
        nxt[r * TN + t] = acc[kk];
        tot[r * TN + t] += acc[kk];
    }
}

// ---------------- detection ----------------

__global__ void detect_kernel(const float* __restrict__ tot, const float* __restrict__ w,
                              const int* __restrict__ dd, float* __restrict__ det) {
    int t = blockIdx.x * 256 + threadIdx.x;
    int r0 = blockIdx.y * 64;
    float acc = 0.f;
    for (int r = r0; r < r0 + 64; ++r) {
        int d = dd[r];
        int idx = t - d;
        if (idx < 0) idx += TN;
        acc = fmaf(w[r], tot[r * TN + idx], acc);
    }
    atomicAdd(&det[t], acc);
}

__global__ void final_kernel(const float* __restrict__ det, float* __restrict__ out) {
    int t = blockIdx.x * 256 + threadIdx.x;
    if (t < TN) out[t] = det[t] * __expf(-LOG_GAMMA * (float)t * INV_SR);
}

// ---------------- launch ----------------

extern "C" void kernel_launch(void* const* d_in, const int* in_sizes, int n_in,
                              void* d_out, int out_size, void* d_ws, size_t ws_size,
                              hipStream_t stream) {
    const float* init_rad   = (const float*)d_in[0];
    const float* basis      = (const float*)d_in[1];
    const float* absorption = (const float*)d_in[2];
    const float* scattering = (const float*)d_in[3];
    const float* det_w      = (const float*)d_in[4];
    const int*   row        = (const int*)d_in[5];
    const int*   col        = (const int*)d_in[6];
    const int*   rid        = (const int*)d_in[7];
    const int*   delay      = (const int*)d_in[8];
    const int*   det_delay  = (const int*)d_in[9];
    float* out = (float*)d_out;

    char* ws = (char*)d_ws;
    size_t o = 0;
    auto alloc = [&](size_t bytes) {
        void* p = ws + o;
        o = (o + bytes + 255) & ~(size_t)255;
        return p;
    };
    int*   cnt    = (int*)alloc(RN * 4);
    int*   off    = (int*)alloc((RN + 1) * 4);
    int*   cursor = (int*)alloc(RN * 4);
    int*   packed = (int*)alloc(EN * 4);
    float* kernv  = (float*)alloc(EN * 4);
    float* bufA   = (float*)alloc((size_t)RN * TN * 4);
    float* bufB   = (float*)alloc((size_t)RN * TN * 4);
    float* tot    = (float*)alloc((size_t)RN * TN * 4);
    float* det    = (float*)alloc(TN * 4);

    hipMemsetAsync(cnt, 0, RN * 4, stream);
    hipMemsetAsync(det, 0, TN * 4, stream);

    hist_kernel<<<EN / 256, 256, 0, stream>>>(row, cnt);
    scan_kernel<<<1, 1024, 0, stream>>>(cnt, off, cursor);
    scatter_kernel<<<EN / 256, 256, 0, stream>>>(row, col, rid, delay, basis,
                                                 absorption, scattering, cursor,
                                                 packed, kernv);
    init_kernel<<<(RN * TN / 4 + 255) / 256, 256, 0, stream>>>(init_rad, bufA, tot);

    float* cur = bufA;
    float* nxt = bufB;
    for (int b = 0; b < NBOUNCE; ++b) {
        bounce_kernel<<<RN, 256, 0, stream>>>(cur, nxt, tot, off, packed, kernv);
        float* tmp = cur; cur = nxt; nxt = tmp;
    }

    detect_kernel<<<dim3(TN / 256, RN / 64), 256, 0, stream>>>(tot, det_w, det_delay, det);
    final_kernel<<<TN / 256, 256, 0, stream>>>(det, out);
}

// Round 2
// 742.938 us; speedup vs baseline: 1.9502x; 1.9502x over previous
//
#include <hip/hip_runtime.h>
#include <hip/hip_bf16.h>
#include <hip/hip_fp16.h>

#define RN 4096
#define EN 131072
#define TN 1536
#define PN 256
#define NBOUNCE 12
// np.float32(np.log(1e-3))
#define LOG_GAMMA -6.90775528f
#define INV_SR (1.0f / 16000.0f)

// ---------------- CSR build ----------------

__global__ void hist_kernel(const int* __restrict__ row, int* __restrict__ cnt) {
    int e = blockIdx.x * blockDim.x + threadIdx.x;
    if (e < EN) atomicAdd(&cnt[row[e]], 1);
}

// single block, 1024 threads: exclusive scan of cnt[0..RN) -> off[0..RN], off[RN]=EN
__global__ void scan_kernel(const int* __restrict__ cnt, int* __restrict__ off,
                            int* __restrict__ cursor) {
    __shared__ int part[1024];
    int tid = threadIdx.x;
    int v0 = cnt[tid * 4 + 0], v1 = cnt[tid * 4 + 1];
    int v2 = cnt[tid * 4 + 2], v3 = cnt[tid * 4 + 3];
    part[tid] = v0 + v1 + v2 + v3;
    __syncthreads();
    for (int ofs = 1; ofs < 1024; ofs <<= 1) {
        int x = (tid >= ofs) ? part[tid - ofs] : 0;
        __syncthreads();
        part[tid] += x;
        __syncthreads();
    }
    int excl = (tid == 0) ? 0 : part[tid - 1];
    int o0 = excl, o1 = o0 + v0, o2 = o1 + v1, o3 = o2 + v2;
    off[tid * 4 + 0] = o0; cursor[tid * 4 + 0] = o0;
    off[tid * 4 + 1] = o1; cursor[tid * 4 + 1] = o1;
    off[tid * 4 + 2] = o2; cursor[tid * 4 + 2] = o2;
    off[tid * 4 + 3] = o3; cursor[tid * 4 + 3] = o3;
    if (tid == 1023) off[RN] = o3 + v3;
}

// per edge: compute kernel value, place (col|delay<<12, kern) into CSR slot
__global__ void scatter_kernel(const int* __restrict__ row, const int* __restrict__ col,
                               const int* __restrict__ rid, const int* __restrict__ delay,
                               const float* __restrict__ basis,
                               const float* __restrict__ absorption,
                               const float* __restrict__ scattering,
                               int* __restrict__ cursor,
                               int* __restrict__ packed, float* __restrict__ kernv) {
    int e = blockIdx.x * blockDim.x + threadIdx.x;
    if (e >= EN) return;
    int p = rid[e];
    float a = absorption[p];
    float s = scattering[p];
    float k = (1.0f - a) * (s * basis[e] + (1.0f - s) * basis[EN + e]);
    int r = row[e];
    int pos = atomicAdd(&cursor[r], 1);
    packed[pos] = col[e] | (delay[e] << 12);
    kernv[pos] = k;
}

// ---------------- init: cur = tot = half(x * window) ----------------

__global__ void init_kernel(const float* __restrict__ x, __half* __restrict__ cur,
                            __half* __restrict__ tot) {
    int g = blockIdx.x * blockDim.x + threadIdx.x;   // 8 elements per thread
    if (g >= RN * TN / 8) return;
    int t8 = g % (TN / 8);
    int tbase = t8 * 8;
    const float4 v0 = reinterpret_cast<const float4*>(x)[g * 2 + 0];
    const float4 v1 = reinterpret_cast<const float4*>(x)[g * 2 + 1];
    __half h[8];
    h[0] = __float2half(v0.x * __expf(LOG_GAMMA * (float)(tbase + 0) * INV_SR));
    h[1] = __float2half(v0.y * __expf(LOG_GAMMA * (float)(tbase + 1) * INV_SR));
    h[2] = __float2half(v0.z * __expf(LOG_GAMMA * (float)(tbase + 2) * INV_SR));
    h[3] = __float2half(v0.w * __expf(LOG_GAMMA * (float)(tbase + 3) * INV_SR));
    h[4] = __float2half(v1.x * __expf(LOG_GAMMA * (float)(tbase + 4) * INV_SR));
    h[5] = __float2half(v1.y * __expf(LOG_GAMMA * (float)(tbase + 5) * INV_SR));
    h[6] = __float2half(v1.z * __expf(LOG_GAMMA * (float)(tbase + 6) * INV_SR));
    h[7] = __float2half(v1.w * __expf(LOG_GAMMA * (float)(tbase + 7) * INV_SR));
    float4 packed = *reinterpret_cast<float4*>(h);
    reinterpret_cast<float4*>(cur)[g] = packed;
    reinterpret_cast<float4*>(tot)[g] = packed;
}

// ---------------- bounce: nxt[r,t] = sum_e kern*cur[col,(t-d) mod T]; tot += nxt ----

__global__ __launch_bounds__(256) void bounce_kernel(
        const __half* __restrict__ cur, __half* __restrict__ nxt, __half* __restrict__ tot,
        const int* __restrict__ off, const int* __restrict__ packed,
        const float* __restrict__ kernv) {
    int r = blockIdx.x;
    int tid = threadIdx.x;
    int e0 = off[r], e1 = off[r + 1];
    float acc[6] = {0.f, 0.f, 0.f, 0.f, 0.f, 0.f};
    __shared__ int   s_pk[128];
    __shared__ float s_kv[128];
    for (int base = e0; base < e1; base += 128) {
        int n = min(128, e1 - base);
        __syncthreads();
        if (tid < n) { s_pk[tid] = packed[base + tid]; s_kv[tid] = kernv[base + tid]; }
        __syncthreads();
        for (int j = 0; j < n; ++j) {
            int pk = s_pk[j];
            int c = pk & 4095;
            int d = pk >> 12;
            float k = s_kv[j];
            const __half* rowp = cur + c * TN;
            int u = tid - d + TN;                 // [1025, 1791]
#pragma unroll
            for (int kk = 0; kk < 6; ++kk) {
                int idx = u + kk * 256;           // max 3071 < 2*TN
                if (idx >= TN) idx -= TN;
                acc[kk] = fmaf(k, __half2float(rowp[idx]), acc[kk]);
            }
        }
    }
#pragma unroll
    for (int kk = 0; kk < 6; ++kk) {
        int t = tid + kk * 256;
        nxt[r * TN + t] = __float2half(acc[kk]);
        int ti = r * TN + t;
        tot[ti] = __float2half(__half2float(tot[ti]) + acc[kk]);
    }
}

// ---------------- detection ----------------

__global__ void detect_kernel(const __half* __restrict__ tot, const float* __restrict__ w,
                              const int* __restrict__ dd, float* __restrict__ det) {
    int t = blockIdx.x * 256 + threadIdx.x;
    int r0 = blockIdx.y * 64;
    float acc = 0.f;
    for (int r = r0; r < r0 + 64; ++r) {
        int d = dd[r];
        int idx = t - d;
        if (idx < 0) idx += TN;
        acc = fmaf(w[r], __half2float(tot[r * TN + idx]), acc);
    }
    atomicAdd(&det[t], acc);
}

__global__ void final_kernel(const float* __restrict__ det, float* __restrict__ out) {
    int t = blockIdx.x * 256 + threadIdx.x;
    if (t < TN) out[t] = det[t] * __expf(-LOG_GAMMA * (float)t * INV_SR);
}

// ---------------- launch ----------------

extern "C" void kernel_launch(void* const* d_in, const int* in_sizes, int n_in,
                              void* d_out, int out_size, void* d_ws, size_t ws_size,
                              hipStream_t stream) {
    const float* init_rad   = (const float*)d_in[0];
    const float* basis      = (const float*)d_in[1];
    const float* absorption = (const float*)d_in[2];
    const float* scattering = (const float*)d_in[3];
    const float* det_w      = (const float*)d_in[4];
    const int*   row        = (const int*)d_in[5];
    const int*   col        = (const int*)d_in[6];
    const int*   rid        = (const int*)d_in[7];
    const int*   delay      = (const int*)d_in[8];
    const int*   det_delay  = (const int*)d_in[9];
    float* out = (float*)d_out;

    char* ws = (char*)d_ws;
    size_t o = 0;
    auto alloc = [&](size_t bytes) {
        void* p = ws + o;
        o = (o + bytes + 255) & ~(size_t)255;
        return p;
    };
    int*    cnt    = (int*)alloc(RN * 4);
    int*    off    = (int*)alloc((RN + 1) * 4);
    int*    cursor = (int*)alloc(RN * 4);
    int*    packed = (int*)alloc(EN * 4);
    float*  kernv  = (float*)alloc(EN * 4);
    __half* bufA   = (__half*)alloc((size_t)RN * TN * 2);
    __half* bufB   = (__half*)alloc((size_t)RN * TN * 2);
    __half* tot    = (__half*)alloc((size_t)RN * TN * 2);
    float*  det    = (float*)alloc(TN * 4);

    hipMemsetAsync(cnt, 0, RN * 4, stream);
    hipMemsetAsync(det, 0, TN * 4, stream);

    hist_kernel<<<EN / 256, 256, 0, stream>>>(row, cnt);
    scan_kernel<<<1, 1024, 0, stream>>>(cnt, off, cursor);
    scatter_kernel<<<EN / 256, 256, 0, stream>>>(row, col, rid, delay, basis,
                                                 absorption, scattering, cursor,
                                                 packed, kernv);
    init_kernel<<<(RN * TN / 8 + 255) / 256, 256, 0, stream>>>(init_rad, bufA, tot);

    __half* cur = bufA;
    __half* nxt = bufB;
    for (int b = 0; b < NBOUNCE; ++b) {
        bounce_kernel<<<RN, 256, 0, stream>>>(cur, nxt, tot, off, packed, kernv);
        __half* tmp = cur; cur = nxt; nxt = tmp;
    }

    detect_kernel<<<dim3(TN / 256, RN / 64), 256, 0, stream>>>(tot, det_w, det_delay, det);
    final_kernel<<<TN / 256, 256, 0, stream>>>(det, out);
}